// Round 13
// baseline (311.582 us; speedup 1.0000x reference)
//
#include <hip/hip_runtime.h>
#include <math.h>

#define FFT_N   4096
#define THREADS 256
#define PADN    4352    // max pad4 index 4347
#define GRID    768     // 3 blocks/CU * 256 CUs; persistent, each ~10-11 pairs
#define NPAIRS  8192

// R9 champion LDS layout: additive pad pad4(i) = i + 4*(i>>6).
//  A (i=t+256k):    base [t+4*(t>>6)] + 272k        linear -> ds imm, 2-way banks
//  B (i=256a+j+16k): base [272a+j] + 16k+4*(k>>2)   linear -> ds imm, 2-way banks
//  C (i=16t+n):     base [16t+4*(t>>2)] + n         contiguous 16B-aligned -> b128
// R13: persistent blocks; next pair's 32 loads issued right after stage-A's
// LDS write (where the input registers die) so HBM reads overlap B/C/B' compute.

#define REV(r) ((((r) & 3) << 2) | ((r) >> 2))

// gperm[16t + r] = G at local position 16t + REV(r),
// G(p) = ((W[k]+W[(N-k)%N])/2 + 1)/N, k = 3-digit base-16 reversal of p.
__global__ void setup_g_kernel(const float* __restrict__ fw, float* __restrict__ gperm) {
    int p = blockIdx.x * blockDim.x + threadIdx.x;
    if (p >= FFT_N) return;
    int r = p & 15;
    int local = (p & ~15) | REV(r);
    unsigned k = ((local & 15u) << 8) | ((unsigned)local & 0xF0u) | ((unsigned)local >> 8);
    float wk  = fw[k];
    float wnk = fw[(FFT_N - k) & (FFT_N - 1)];
    gperm[p] = (0.5f * (wk + wnk) + 1.0f) * (1.0f / (float)FFT_N);
}

__device__ __forceinline__ void cmul(float& xr, float& xi, float c, float s) {
    float tv = xr; xr = tv * c - xi * s; xi = tv * s + xi * c;
}

__device__ __forceinline__ void bfly4_f(float& ar, float& ai, float& br, float& bi,
                                        float& cr, float& ci, float& dr, float& di) {
    float t0r = ar + cr, t0i = ai + ci;
    float t1r = ar - cr, t1i = ai - ci;
    float t2r = br + dr, t2i = bi + di;
    float t3r = br - dr, t3i = bi - di;
    ar = t0r + t2r; ai = t0i + t2i;
    br = t1r + t3i; bi = t1i - t3r;
    cr = t0r - t2r; ci = t0i - t2i;
    dr = t1r - t3i; di = t1i + t3r;
}
__device__ __forceinline__ void bfly4_i(float& ar, float& ai, float& br, float& bi,
                                        float& cr, float& ci, float& dr, float& di) {
    float t0r = ar + cr, t0i = ai + ci;
    float t1r = ar - cr, t1i = ai - ci;
    float t2r = br + dr, t2i = bi + di;
    float t3r = br - dr, t3i = bi - di;
    ar = t0r + t2r; ai = t0i + t2i;
    br = t1r - t3i; bi = t1i + t3r;
    cr = t0r - t2r; ci = t0i - t2i;
    dr = t1r + t3i; di = t1i - t3r;
}

// In-place forward DFT16 (DIF). Output: slot r holds X[REV(r)].
__device__ __forceinline__ void dft16_f(float xr[16], float xi[16]) {
    const float C1 = 0.9238795325112867f;
    const float S1 = 0.3826834323650898f;
    const float H  = 0.7071067811865476f;
    #pragma unroll
    for (int m = 0; m < 4; ++m)
        bfly4_f(xr[m],xi[m], xr[m+4],xi[m+4], xr[m+8],xi[m+8], xr[m+12],xi[m+12]);
    cmul(xr[5],  xi[5],   C1, -S1);
    cmul(xr[9],  xi[9],    H,  -H);
    cmul(xr[13], xi[13],  S1, -C1);
    cmul(xr[6],  xi[6],    H,  -H);
    cmul(xr[10], xi[10], 0.f, -1.f);
    cmul(xr[14], xi[14],  -H,  -H);
    cmul(xr[7],  xi[7],   S1, -C1);
    cmul(xr[11], xi[11],  -H,  -H);
    cmul(xr[15], xi[15], -C1,  S1);
    #pragma unroll
    for (int g = 0; g < 4; ++g)
        bfly4_f(xr[4*g],xi[4*g], xr[4*g+1],xi[4*g+1], xr[4*g+2],xi[4*g+2], xr[4*g+3],xi[4*g+3]);
}

// In-place inverse DFT16 (unnormalized). Input: slot r holds X[REV(r)].
__device__ __forceinline__ void idft16(float xr[16], float xi[16]) {
    const float C1 = 0.9238795325112867f;
    const float S1 = 0.3826834323650898f;
    const float H  = 0.7071067811865476f;
    #pragma unroll
    for (int g = 0; g < 4; ++g)
        bfly4_i(xr[4*g],xi[4*g], xr[4*g+1],xi[4*g+1], xr[4*g+2],xi[4*g+2], xr[4*g+3],xi[4*g+3]);
    cmul(xr[5],  xi[5],   C1,  S1);
    cmul(xr[9],  xi[9],    H,   H);
    cmul(xr[13], xi[13],  S1,  C1);
    cmul(xr[6],  xi[6],    H,   H);
    cmul(xr[10], xi[10], 0.f, 1.f);
    cmul(xr[14], xi[14],  -H,   H);
    cmul(xr[7],  xi[7],   S1,  C1);
    cmul(xr[11], xi[11],  -H,   H);
    cmul(xr[15], xi[15], -C1, -S1);
    #pragma unroll
    for (int m = 0; m < 4; ++m)
        bfly4_i(xr[m],xi[m], xr[m+4],xi[m+4], xr[m+8],xi[m+8], xr[m+12],xi[m+12]);
}

// apply w^{REV(r)} to slot r; binary-power chain, dependency depth ~5.
__device__ __forceinline__ void twiddle_rev(float xr[16], float xi[16], float ang) {
    float s1, c1; __sincosf(ang, &s1, &c1);
    float c2 = c1*c1 - s1*s1, s2 = 2.f*c1*s1;
    float c3 = c2*c1 - s2*s1, s3 = c2*s1 + s2*c1;
    float c4 = c2*c2 - s2*s2, s4 = 2.f*c2*s2;
    cmul(xr[4],  xi[4],  c1, s1);
    cmul(xr[8],  xi[8],  c2, s2);
    cmul(xr[12], xi[12], c3, s3);
    float bc = c4, bs = s4;
    #pragma unroll
    for (int q = 1; q < 4; ++q) {
        cmul(xr[q], xi[q], bc, bs);
        { float ec = bc*c1 - bs*s1, es = bc*s1 + bs*c1; cmul(xr[4+q],  xi[4+q],  ec, es); }
        { float ec = bc*c2 - bs*s2, es = bc*s2 + bs*c2; cmul(xr[8+q],  xi[8+q],  ec, es); }
        { float ec = bc*c3 - bs*s3, es = bc*s3 + bs*c3; cmul(xr[12+q], xi[12+q], ec, es); }
        if (q < 3) { float nb = bc*c4 - bs*s4; bs = bc*s4 + bs*c4; bc = nb; }
    }
}

__global__ __launch_bounds__(THREADS, 3) void fourier_fft_kernel(
    const float* __restrict__ in, const float* __restrict__ gperm,
    const float* __restrict__ lw, float* __restrict__ out)
{
    __shared__ __align__(16) float re[PADN];
    __shared__ __align__(16) float im[PADN];
    const int t = threadIdx.x;

    const float CFA = -6.28318530717958647692f / 4096.0f;
    const float CFB = -6.28318530717958647692f / 256.0f;

    // per-thread LDS bases (all per-k offsets are compile-time immediates)
    const int baseA = t + 4 * (t >> 6);                        // + 272k
    const int baseB = 272 * (t >> 4) + (t & 15);               // + 16k + 4*(k>>2)
    const int baseC = 16 * t + 4 * (t >> 2);                   // + n (16B-aligned)
    const int jb = t & 15;

    const float angA_f =  CFA * (float)t;
    const float angB_f =  CFB * (float)jb;

    float xr[16], xi[16];   // working pair
    float pr[16], pi[16];   // prefetched next pair

    long long pair = blockIdx.x;

    // initial load: thread t owns x[t + 256n] — coalesced
    {
        const float* r0 = in + pair * (2LL * FFT_N);
        const float* r1 = r0 + FFT_N;
        #pragma unroll
        for (int n = 0; n < 16; ++n) {
            xr[n] = r0[t + 256*n];
            xi[n] = r1[t + 256*n];
        }
    }

    while (true) {
        const long long nxt = pair + GRID;
        const bool has_next = (nxt < NPAIRS);     // uniform across the block

        // ---- forward stage A (L=4096, j=t): slot r holds A[REV(r)]
        dft16_f(xr, xi);
        twiddle_rev(xr, xi, angA_f);
        #pragma unroll
        for (int k = 0; k < 16; ++k) {
            re[baseA + 272*k] = xr[REV(k)];
            im[baseA + 272*k] = xi[REV(k)];
        }
        // xr/xi are dead now: issue next pair's loads; they complete under B/C/B'
        if (has_next) {
            const float* r0 = in + nxt * (2LL * FFT_N);
            const float* r1 = r0 + FFT_N;
            #pragma unroll
            for (int n = 0; n < 16; ++n) {
                pr[n] = r0[t + 256*n];
                pi[n] = r1[t + 256*n];
            }
        }
        __syncthreads();

        // ---- forward stage B (L=256, j=t&15)
        #pragma unroll
        for (int n = 0; n < 16; ++n) {
            int s = baseB + 16*n + 4*(n>>2);
            xr[n] = re[s]; xi[n] = im[s];
        }
        dft16_f(xr, xi);
        twiddle_rev(xr, xi, angB_f);
        #pragma unroll
        for (int k = 0; k < 16; ++k) {
            int s = baseB + 16*k + 4*(k>>2);
            re[s] = xr[REV(k)]; im[s] = xi[REV(k)];
        }
        __syncthreads();

        // ---- forward stage C + pointwise G + inverse stage C', in registers
        #pragma unroll
        for (int q = 0; q < 4; ++q) {
            float4 vr = *(const float4*)&re[baseC + 4*q];
            float4 vi = *(const float4*)&im[baseC + 4*q];
            xr[4*q+0] = vr.x; xr[4*q+1] = vr.y; xr[4*q+2] = vr.z; xr[4*q+3] = vr.w;
            xi[4*q+0] = vi.x; xi[4*q+1] = vi.y; xi[4*q+2] = vi.z; xi[4*q+3] = vi.w;
        }
        dft16_f(xr, xi);
        {
            const float4* gp = (const float4*)(gperm + 16*t);   // REV-permuted
            #pragma unroll
            for (int q = 0; q < 4; ++q) {
                float4 g = gp[q];
                xr[4*q+0] *= g.x; xi[4*q+0] *= g.x;
                xr[4*q+1] *= g.y; xi[4*q+1] *= g.y;
                xr[4*q+2] *= g.z; xi[4*q+2] *= g.z;
                xr[4*q+3] *= g.w; xi[4*q+3] *= g.w;
            }
        }
        idft16(xr, xi);
        #pragma unroll
        for (int q = 0; q < 4; ++q) {
            *(float4*)&re[baseC + 4*q] = make_float4(xr[4*q+0], xr[4*q+1], xr[4*q+2], xr[4*q+3]);
            *(float4*)&im[baseC + 4*q] = make_float4(xi[4*q+0], xi[4*q+1], xi[4*q+2], xi[4*q+3]);
        }
        __syncthreads();

        // ---- inverse stage B'
        #pragma unroll
        for (int k = 0; k < 16; ++k) {
            int s = baseB + 16*k + 4*(k>>2);
            xr[REV(k)] = re[s]; xi[REV(k)] = im[s];
        }
        twiddle_rev(xr, xi, -angB_f);
        idft16(xr, xi);
        #pragma unroll
        for (int n = 0; n < 16; ++n) {
            int s = baseB + 16*n + 4*(n>>2);
            re[s] = xr[n]; im[s] = xi[n];
        }
        __syncthreads();

        // ---- inverse stage A' + epilogue
        #pragma unroll
        for (int k = 0; k < 16; ++k) {
            xr[REV(k)] = re[baseA + 272*k];
            xi[REV(k)] = im[baseA + 272*k];
        }
        twiddle_rev(xr, xi, -angA_f);
        idft16(xr, xi);

        {
            float* o0 = out + pair * (2LL * FFT_N);
            #pragma unroll
            for (int n = 0; n < 16; ++n) {
                int i = t + 256*n;
                float l = lw[i];
                o0[i]         = fmaxf(xr[n]*l, 0.0f);
                o0[FFT_N + i] = fmaxf(xi[n]*l, 0.0f);
            }
        }

        if (!has_next) break;
        // rotate prefetched pair into the working registers
        #pragma unroll
        for (int n = 0; n < 16; ++n) { xr[n] = pr[n]; xi[n] = pi[n]; }
        pair = nxt;
        // protect LDS: next iteration's stage-A writes must not race this
        // iteration's A'-reads in other waves
        __syncthreads();
    }
}

extern "C" void kernel_launch(void* const* d_in, const int* in_sizes, int n_in,
                              void* d_out, int out_size, void* d_ws, size_t ws_size,
                              hipStream_t stream) {
    const float* inputs = (const float*)d_in[0];
    const float* fw     = (const float*)d_in[1];
    const float* lw     = (const float*)d_in[2];
    float* out   = (float*)d_out;
    float* gperm = (float*)d_ws;   // 4096 floats = 16 KB scratch

    hipLaunchKernelGGL(setup_g_kernel, dim3(FFT_N / THREADS), dim3(THREADS), 0, stream,
                       fw, gperm);

    hipLaunchKernelGGL(fourier_fft_kernel, dim3(GRID), dim3(THREADS), 0, stream,
                       inputs, gperm, lw, out);
}

// Round 14
// 116.224 us; speedup vs baseline: 2.6809x; 2.6809x over previous
//
#include <hip/hip_runtime.h>
#include <math.h>

#define FFT_N   4096
#define THREADS 256
#define PADN    4352   // max pad4 index 4347

// R9 champion LDS layout: additive pad pad4(i) = i + 4*(i>>6).
//  A (i=t+256k):    base [t+4*(t>>6)] + 272k        linear -> ds imm, 2-way banks
//  B (i=256a+j+16k): base [272a+j] + 16k+4*(k>>2)   linear -> ds imm, 2-way banks
//  C (i=16t+n):     base [16t+4*(t>>2)] + n         contiguous 16B-aligned -> b128
//
// R14: barrier diet. Stage-B/C/C'/B' slot sets of thread t all live in
// hi-block H=t>>4 (slot range [272H, 272H+271]); a wave owns hi-blocks
// 4w..4w+3 exclusively for the whole middle section -> the B->C and C'->B'
// exchanges are INTRA-WAVE, ordered by same-thread LDS dependencies
// (compiler-inserted lgkmcnt). Only A->B and B'->A' cross waves: 2 barriers
// per pair instead of 4; the whole VALU-heavy middle is barrier-free so
// waves slip and their global I/O overlaps other waves' compute.

#define REV(r) ((((r) & 3) << 2) | ((r) >> 2))

// gperm[16t + r] = G at local position 16t + REV(r),
// G(p) = ((W[k]+W[(N-k)%N])/2 + 1)/N, k = 3-digit base-16 reversal of p.
__global__ void setup_g_kernel(const float* __restrict__ fw, float* __restrict__ gperm) {
    int p = blockIdx.x * blockDim.x + threadIdx.x;
    if (p >= FFT_N) return;
    int r = p & 15;
    int local = (p & ~15) | REV(r);
    unsigned k = ((local & 15u) << 8) | ((unsigned)local & 0xF0u) | ((unsigned)local >> 8);
    float wk  = fw[k];
    float wnk = fw[(FFT_N - k) & (FFT_N - 1)];
    gperm[p] = (0.5f * (wk + wnk) + 1.0f) * (1.0f / (float)FFT_N);
}

__device__ __forceinline__ void cmul(float& xr, float& xi, float c, float s) {
    float tv = xr; xr = tv * c - xi * s; xi = tv * s + xi * c;
}

__device__ __forceinline__ void bfly4_f(float& ar, float& ai, float& br, float& bi,
                                        float& cr, float& ci, float& dr, float& di) {
    float t0r = ar + cr, t0i = ai + ci;
    float t1r = ar - cr, t1i = ai - ci;
    float t2r = br + dr, t2i = bi + di;
    float t3r = br - dr, t3i = bi - di;
    ar = t0r + t2r; ai = t0i + t2i;
    br = t1r + t3i; bi = t1i - t3r;
    cr = t0r - t2r; ci = t0i - t2i;
    dr = t1r - t3i; di = t1i + t3r;
}
__device__ __forceinline__ void bfly4_i(float& ar, float& ai, float& br, float& bi,
                                        float& cr, float& ci, float& dr, float& di) {
    float t0r = ar + cr, t0i = ai + ci;
    float t1r = ar - cr, t1i = ai - ci;
    float t2r = br + dr, t2i = bi + di;
    float t3r = br - dr, t3i = bi - di;
    ar = t0r + t2r; ai = t0i + t2i;
    br = t1r - t3i; bi = t1i + t3r;
    cr = t0r - t2r; ci = t0i - t2i;
    dr = t1r + t3i; di = t1i - t3r;
}

// In-place forward DFT16 (DIF). Output: slot r holds X[REV(r)].
__device__ __forceinline__ void dft16_f(float xr[16], float xi[16]) {
    const float C1 = 0.9238795325112867f;
    const float S1 = 0.3826834323650898f;
    const float H  = 0.7071067811865476f;
    #pragma unroll
    for (int m = 0; m < 4; ++m)
        bfly4_f(xr[m],xi[m], xr[m+4],xi[m+4], xr[m+8],xi[m+8], xr[m+12],xi[m+12]);
    cmul(xr[5],  xi[5],   C1, -S1);
    cmul(xr[9],  xi[9],    H,  -H);
    cmul(xr[13], xi[13],  S1, -C1);
    cmul(xr[6],  xi[6],    H,  -H);
    cmul(xr[10], xi[10], 0.f, -1.f);
    cmul(xr[14], xi[14],  -H,  -H);
    cmul(xr[7],  xi[7],   S1, -C1);
    cmul(xr[11], xi[11],  -H,  -H);
    cmul(xr[15], xi[15], -C1,  S1);
    #pragma unroll
    for (int g = 0; g < 4; ++g)
        bfly4_f(xr[4*g],xi[4*g], xr[4*g+1],xi[4*g+1], xr[4*g+2],xi[4*g+2], xr[4*g+3],xi[4*g+3]);
}

// In-place inverse DFT16 (unnormalized). Input: slot r holds X[REV(r)].
__device__ __forceinline__ void idft16(float xr[16], float xi[16]) {
    const float C1 = 0.9238795325112867f;
    const float S1 = 0.3826834323650898f;
    const float H  = 0.7071067811865476f;
    #pragma unroll
    for (int g = 0; g < 4; ++g)
        bfly4_i(xr[4*g],xi[4*g], xr[4*g+1],xi[4*g+1], xr[4*g+2],xi[4*g+2], xr[4*g+3],xi[4*g+3]);
    cmul(xr[5],  xi[5],   C1,  S1);
    cmul(xr[9],  xi[9],    H,   H);
    cmul(xr[13], xi[13],  S1,  C1);
    cmul(xr[6],  xi[6],    H,   H);
    cmul(xr[10], xi[10], 0.f, 1.f);
    cmul(xr[14], xi[14],  -H,   H);
    cmul(xr[7],  xi[7],   S1,  C1);
    cmul(xr[11], xi[11],  -H,   H);
    cmul(xr[15], xi[15], -C1, -S1);
    #pragma unroll
    for (int m = 0; m < 4; ++m)
        bfly4_i(xr[m],xi[m], xr[m+4],xi[m+4], xr[m+8],xi[m+8], xr[m+12],xi[m+12]);
}

// apply w^{REV(r)} to slot r; binary-power chain, dependency depth ~5.
__device__ __forceinline__ void twiddle_rev(float xr[16], float xi[16], float ang) {
    float s1, c1; __sincosf(ang, &s1, &c1);
    float c2 = c1*c1 - s1*s1, s2 = 2.f*c1*s1;
    float c3 = c2*c1 - s2*s1, s3 = c2*s1 + s2*c1;
    float c4 = c2*c2 - s2*s2, s4 = 2.f*c2*s2;
    cmul(xr[4],  xi[4],  c1, s1);
    cmul(xr[8],  xi[8],  c2, s2);
    cmul(xr[12], xi[12], c3, s3);
    float bc = c4, bs = s4;
    #pragma unroll
    for (int q = 1; q < 4; ++q) {
        cmul(xr[q], xi[q], bc, bs);
        { float ec = bc*c1 - bs*s1, es = bc*s1 + bs*c1; cmul(xr[4+q],  xi[4+q],  ec, es); }
        { float ec = bc*c2 - bs*s2, es = bc*s2 + bs*c2; cmul(xr[8+q],  xi[8+q],  ec, es); }
        { float ec = bc*c3 - bs*s3, es = bc*s3 + bs*c3; cmul(xr[12+q], xi[12+q], ec, es); }
        if (q < 3) { float nb = bc*c4 - bs*s4; bs = bc*s4 + bs*c4; bc = nb; }
    }
}

__global__ __launch_bounds__(THREADS, 4) void fourier_fft_kernel(
    const float* __restrict__ in, const float* __restrict__ gperm,
    const float* __restrict__ lw, float* __restrict__ out)
{
    __shared__ __align__(16) float re[PADN];
    __shared__ __align__(16) float im[PADN];
    const int t = threadIdx.x;
    const long long pair = blockIdx.x;
    const float* r0 = in + pair * (2LL * FFT_N);
    const float* r1 = r0 + FFT_N;

    const float CFA = -6.28318530717958647692f / 4096.0f;
    const float CFB = -6.28318530717958647692f / 256.0f;

    // per-thread LDS bases (all per-k offsets are compile-time immediates)
    const int baseA = t + 4 * (t >> 6);                        // + 272k
    const int baseB = 272 * (t >> 4) + (t & 15);               // + 16k + 4*(k>>2)
    const int baseC = 16 * t + 4 * (t >> 2);                   // + n (16B-aligned)
    const int jb = t & 15;

    float xr[16], xi[16];

    // load: thread t owns x[t + 256n] — coalesced
    #pragma unroll
    for (int n = 0; n < 16; ++n) {
        xr[n] = r0[t + 256*n];
        xi[n] = r1[t + 256*n];
    }

    // ---- forward stage A (L=4096, j=t): slot r holds A[REV(r)]
    dft16_f(xr, xi);
    twiddle_rev(xr, xi, CFA * (float)t);
    #pragma unroll
    for (int k = 0; k < 16; ++k) {
        re[baseA + 272*k] = xr[REV(k)];
        im[baseA + 272*k] = xi[REV(k)];
    }
    __syncthreads();   // A->B crosses waves

    // ---- forward stage B (L=256, j=t&15)
    #pragma unroll
    for (int n = 0; n < 16; ++n) {
        int s = baseB + 16*n + 4*(n>>2);
        xr[n] = re[s]; xi[n] = im[s];
    }
    dft16_f(xr, xi);
    twiddle_rev(xr, xi, CFB * (float)jb);
    #pragma unroll
    for (int k = 0; k < 16; ++k) {
        int s = baseB + 16*k + 4*(k>>2);
        re[s] = xr[REV(k)]; im[s] = xi[REV(k)];
    }
    // NO barrier: B->C exchange is intra-wave (hi-block t>>4 owned by wave)

    // ---- forward stage C + pointwise G + inverse stage C', all in registers.
    #pragma unroll
    for (int q = 0; q < 4; ++q) {
        float4 vr = *(const float4*)&re[baseC + 4*q];
        float4 vi = *(const float4*)&im[baseC + 4*q];
        xr[4*q+0] = vr.x; xr[4*q+1] = vr.y; xr[4*q+2] = vr.z; xr[4*q+3] = vr.w;
        xi[4*q+0] = vi.x; xi[4*q+1] = vi.y; xi[4*q+2] = vi.z; xi[4*q+3] = vi.w;
    }
    dft16_f(xr, xi);
    {
        const float4* gp = (const float4*)(gperm + 16*t);   // already REV-permuted
        #pragma unroll
        for (int q = 0; q < 4; ++q) {
            float4 g = gp[q];
            xr[4*q+0] *= g.x; xi[4*q+0] *= g.x;
            xr[4*q+1] *= g.y; xi[4*q+1] *= g.y;
            xr[4*q+2] *= g.z; xi[4*q+2] *= g.z;
            xr[4*q+3] *= g.w; xi[4*q+3] *= g.w;
        }
    }
    idft16(xr, xi);
    #pragma unroll
    for (int q = 0; q < 4; ++q) {
        *(float4*)&re[baseC + 4*q] = make_float4(xr[4*q+0], xr[4*q+1], xr[4*q+2], xr[4*q+3]);
        *(float4*)&im[baseC + 4*q] = make_float4(xi[4*q+0], xi[4*q+1], xi[4*q+2], xi[4*q+3]);
    }
    // NO barrier: C'->B' exchange is intra-wave

    // ---- inverse stage B': load digit-reversed, conj twiddle, idft16
    #pragma unroll
    for (int k = 0; k < 16; ++k) {
        int s = baseB + 16*k + 4*(k>>2);
        xr[REV(k)] = re[s]; xi[REV(k)] = im[s];
    }
    twiddle_rev(xr, xi, -CFB * (float)jb);
    idft16(xr, xi);
    #pragma unroll
    for (int n = 0; n < 16; ++n) {
        int s = baseB + 16*n + 4*(n>>2);
        re[s] = xr[n]; im[s] = xi[n];
    }
    __syncthreads();   // B'->A' crosses waves

    // ---- inverse stage A' + epilogue straight from registers
    #pragma unroll
    for (int k = 0; k < 16; ++k) {
        xr[REV(k)] = re[baseA + 272*k];
        xi[REV(k)] = im[baseA + 272*k];
    }
    twiddle_rev(xr, xi, -CFA * (float)t);
    idft16(xr, xi);

    float* o0 = out + pair * (2LL * FFT_N);
    #pragma unroll
    for (int n = 0; n < 16; ++n) {
        int i = t + 256*n;
        float l = lw[i];
        o0[i]         = fmaxf(xr[n]*l, 0.0f);
        o0[FFT_N + i] = fmaxf(xi[n]*l, 0.0f);
    }
}

extern "C" void kernel_launch(void* const* d_in, const int* in_sizes, int n_in,
                              void* d_out, int out_size, void* d_ws, size_t ws_size,
                              hipStream_t stream) {
    const float* inputs = (const float*)d_in[0];
    const float* fw     = (const float*)d_in[1];
    const float* lw     = (const float*)d_in[2];
    float* out   = (float*)d_out;
    float* gperm = (float*)d_ws;   // 4096 floats = 16 KB scratch

    hipLaunchKernelGGL(setup_g_kernel, dim3(FFT_N / THREADS), dim3(THREADS), 0, stream,
                       fw, gperm);

    const int pairs = in_sizes[0] / (2 * FFT_N);   // 16384 rows -> 8192 pairs
    hipLaunchKernelGGL(fourier_fft_kernel, dim3(pairs), dim3(THREADS), 0, stream,
                       inputs, gperm, lw, out);
}